// Round 10
// baseline (1360.885 us; speedup 1.0000x reference)
//
#include <hip/hip_runtime.h>
#include <math.h>

typedef unsigned short u16;
typedef short s16x8 __attribute__((ext_vector_type(8)));
typedef float f32x4 __attribute__((ext_vector_type(4)));

#define BM 128
#define BN 128
#define BK 32

__device__ __forceinline__ u16 f2bf(float f) {
    union { float f; unsigned u; } v; v.f = f;
    unsigned u = v.u + 0x7FFFu + ((v.u >> 16) & 1u);
    return (u16)(u >> 16);
}
__device__ __forceinline__ float bf2f(u16 u) {
    union { unsigned u; float f; } v; v.u = ((unsigned)u) << 16; return v.f;
}

__device__ __forceinline__ void g2lds16(const void* g, void* l) {
    __builtin_amdgcn_global_load_lds(
        (const __attribute__((address_space(1))) void*)g,
        (__attribute__((address_space(3))) void*)l, 16, 0, 0);
}

enum { E_F32 = 0, E_BF16 = 1, E_QKV = 2, E_SMIX = 3 };

// ============================================================================
// 256x256-tile, BK=32, ring-of-4 LDS slots, 3-tile-deep counted-vmcnt pipeline.
// Per iter T: vmcnt(8) [tile T landed; T+1,T+2 in flight] -> barrier ->
// stage tile T+3 [slot last read at T-1, safe past this barrier] -> 32 MFMA.
// Grid (64,1,G); rect per-XCD block map (2 A-panels + 4 B-panels per XCD).
// LDS rows are 64B; swizzle: granule' = g ^ ((row>>1)&3)  (involution).
// ============================================================================
template<int EPI>
__global__ __launch_bounds__(512) void gemm256_nt(
    const u16* __restrict__ A, const u16* __restrict__ B,
    long sAz, long sBz, int lda, int ldb, int K,
    u16* __restrict__ outb, u16* __restrict__ outb2,
    const u16* __restrict__ aux1b, long sOz, int ldc)
{
    __shared__ __align__(16) u16 As[4][8192];
    __shared__ __align__(16) u16 Bs[4][8192];

    const int z   = blockIdx.z;
    const u16* Ab = A + (long)z * sAz;
    const u16* Bb = B + (long)z * sBz;
    const int t    = threadIdx.x;
    const int lane = t & 63;
    const int wid  = t >> 6;
    const int wm   = wid >> 2;   // 0..1
    const int wn   = wid & 3;    // 0..3
    const int fr   = lane & 15;
    const int g4   = lane >> 4;

    // rect XCD map: XCD r = bx&7 owns m-blocks {2(r&3),2(r&3)+1} x n-blocks {4(r>>2)..+3}
    const int bx = blockIdx.x;            // 0..63
    const int r_ = bx & 7, j_ = bx >> 3;  // j_ in [0,8)
    const int m0 = (2 * (r_ & 3) + (j_ & 1)) * 256;
    const int n0 = (4 * (r_ >> 2) + (j_ >> 1)) * 256;

    // staging: per tile per operand: 2 passes x 512thr x 16B; source pre-swizzled
    const int srow = t >> 2;                          // 0..127
    const int sc   = (((t & 3) ^ ((t >> 3) & 3)) * 8);  // swizzled source col (elems)
    const u16* pA0 = Ab + (long)(m0 + srow) * lda + sc;
    const u16* pA1 = Ab + (long)(m0 + 128 + srow) * lda + sc;
    const u16* pB0 = Bb + (long)(n0 + srow) * ldb + sc;
    const u16* pB1 = Bb + (long)(n0 + 128 + srow) * ldb + sc;
    const int e0 = t * 8, e1 = t * 8 + 4096;

#define STG(s, kk)                          \
    do {                                    \
        g2lds16(pA0 + (kk), &As[s][e0]);    \
        g2lds16(pA1 + (kk), &As[s][e1]);    \
        g2lds16(pB0 + (kk), &Bs[s][e0]);    \
        g2lds16(pB1 + (kk), &Bs[s][e1]);    \
    } while (0)

    // ds_read offsets: row*32 + (g4 ^ ((fr>>1)&3))*8 elements
    const int gsw = (g4 ^ ((fr >> 1) & 3)) * 8;

    f32x4 acc[8][4];
#pragma unroll
    for (int i = 0; i < 8; ++i)
#pragma unroll
        for (int j = 0; j < 4; ++j) acc[i][j] = (f32x4){0.f, 0.f, 0.f, 0.f};

    const int NT = K >> 5;   // K/32, = 64 for K=2048
    STG(0, 0);
    STG(1, 32);
    STG(2, 64);
    for (int T = 0; T < NT; ++T) {
        if (T + 2 < NT)      asm volatile("s_waitcnt vmcnt(8)" ::: "memory");
        else if (T + 1 < NT) asm volatile("s_waitcnt vmcnt(4)" ::: "memory");
        else                 asm volatile("s_waitcnt vmcnt(0)" ::: "memory");
        __builtin_amdgcn_s_barrier();
        if (T + 3 < NT) STG((T + 3) & 3, (T + 3) << 5);

        const u16* Ah = &As[T & 3][0];
        const u16* Bh = &Bs[T & 3][0];
        __builtin_amdgcn_s_setprio(1);
        s16x8 bv[4];
#pragma unroll
        for (int fn = 0; fn < 4; ++fn)
            bv[fn] = *(const s16x8*)(const void*)(Bh + (wn * 64 + fn * 16 + fr) * 32 + gsw);
#pragma unroll
        for (int fm = 0; fm < 8; ++fm) {
            s16x8 av = *(const s16x8*)(const void*)(Ah + (wm * 128 + fm * 16 + fr) * 32 + gsw);
#pragma unroll
            for (int fn = 0; fn < 4; ++fn)
                acc[fm][fn] = __builtin_amdgcn_mfma_f32_16x16x32_bf16(av, bv[fn], acc[fm][fn], 0, 0, 0);
        }
        __builtin_amdgcn_s_setprio(0);
    }
#undef STG

#pragma unroll
    for (int fm = 0; fm < 8; ++fm) {
#pragma unroll
        for (int r = 0; r < 4; ++r) {
            const int gm = m0 + wm * 128 + fm * 16 + g4 * 4 + r;
#pragma unroll
            for (int fn = 0; fn < 4; ++fn) {
                const int gn = n0 + wn * 64 + fn * 16 + fr;
                const float v = acc[fm][fn][r];
                const long off = (long)z * sOz + (long)gm * ldc + gn;
                if (EPI == E_BF16) {
                    outb[off] = f2bf(v);
                } else {  // E_SMIX
                    const float pre = bf2f(aux1b[off]);
                    outb[off]  = f2bf(pre + 0.5f * __logf(v + 1e-6f));
                    outb2[off] = f2bf(v);
                }
            }
        }
    }
}

// ============================================================================
// Fused final: y = A@v1 + w*(C2@v2).  BM=64, BN=64(=dk), BK=64, 4 waves.
// ============================================================================
__global__ __launch_bounds__(256) void gemm_y(
    const u16* __restrict__ Amat,   // final attention A  [z][2048][2048]
    const u16* __restrict__ C2mat,  // C2                 [z][2048][2048]
    const u16* __restrict__ V1t,    // [z][64][2048]
    const u16* __restrict__ V2t,    // [z][64][2048]
    u16* __restrict__ yout,         // [B][2048][512]
    const float* __restrict__ chainp, int zbase)
{
    __shared__ __align__(16) u16 Aa[2][4096];
    __shared__ __align__(16) u16 Ac[2][4096];
    __shared__ __align__(16) u16 B1[2][4096];
    __shared__ __align__(16) u16 B2[2][4096];

    const long NNl = 2048L * 2048;
    const long NDl = 2048L * 64;
    const int z = blockIdx.z;
    const u16* Ab  = Amat  + z * NNl;
    const u16* Cb  = C2mat + z * NNl;
    const u16* V1b = V1t + z * NDl;
    const u16* V2b = V2t + z * NDl;

    const int t = threadIdx.x;
    const int lane = t & 63, wv = t >> 6;   // 4 waves
    const int fr = lane & 15, g4 = lane >> 4;
    const int m0 = blockIdx.x * 64;

    const int sr = t >> 3;
    const int sg = t & 7;
    const int c0 = (sg ^ (sr & 7)) * 8;
    const int c1 = (sg ^ ((sr + 32) & 7)) * 8;
    const u16* pAa0 = Ab  + (long)(m0 + sr) * 2048 + c0;
    const u16* pAa1 = Ab  + (long)(m0 + 32 + sr) * 2048 + c1;
    const u16* pAc0 = Cb  + (long)(m0 + sr) * 2048 + c0;
    const u16* pAc1 = Cb  + (long)(m0 + 32 + sr) * 2048 + c1;
    const u16* pB10 = V1b + (long)sr * 2048 + c0;
    const u16* pB11 = V1b + (long)(32 + sr) * 2048 + c1;
    const u16* pB20 = V2b + (long)sr * 2048 + c0;
    const u16* pB21 = V2b + (long)(32 + sr) * 2048 + c1;
    const int e0 = t * 8, e1 = t * 8 + 2048;

#define STAGEY(d, kk)                          \
    do {                                       \
        g2lds16(pAa0 + (kk), &Aa[d][e0]);      \
        g2lds16(pAa1 + (kk), &Aa[d][e1]);      \
        g2lds16(pAc0 + (kk), &Ac[d][e0]);      \
        g2lds16(pAc1 + (kk), &Ac[d][e1]);      \
        g2lds16(pB10 + (kk), &B1[d][e0]);      \
        g2lds16(pB11 + (kk), &B1[d][e1]);      \
        g2lds16(pB20 + (kk), &B2[d][e0]);      \
        g2lds16(pB21 + (kk), &B2[d][e1]);      \
    } while (0)

    const int swz  = fr & 7;
    const int rbS0 = fr * 64 + ((g4 ^ swz) * 8);
    const int rbS1 = fr * 64 + (((4 + g4) ^ swz) * 8);
    const int arow = wv * 16;

    f32x4 acc1[4], acc2[4];
#pragma unroll
    for (int j = 0; j < 4; ++j) { acc1[j] = (f32x4){0,0,0,0}; acc2[j] = (f32x4){0,0,0,0}; }

    STAGEY(0, 0);
    for (int T = 0; T < 32; ++T) {
        const int d = T & 1;
        if (T + 1 < 32) {
            STAGEY(d ^ 1, (T + 1) << 6);
            asm volatile("s_waitcnt vmcnt(8)" ::: "memory");
        } else {
            asm volatile("s_waitcnt vmcnt(0)" ::: "memory");
        }
        __builtin_amdgcn_s_barrier();
        __builtin_amdgcn_sched_barrier(0);
        __builtin_amdgcn_s_setprio(1);
        {
            s16x8 a1[2], a2[2];
            a1[0] = *(const s16x8*)(const void*)(&Aa[d][arow * 64 + rbS0]);
            a1[1] = *(const s16x8*)(const void*)(&Aa[d][arow * 64 + rbS1]);
            a2[0] = *(const s16x8*)(const void*)(&Ac[d][arow * 64 + rbS0]);
            a2[1] = *(const s16x8*)(const void*)(&Ac[d][arow * 64 + rbS1]);
#pragma unroll
            for (int fn = 0; fn < 4; ++fn) {
                s16x8 b1a = *(const s16x8*)(const void*)(&B1[d][fn * 1024 + rbS0]);
                s16x8 b1b = *(const s16x8*)(const void*)(&B1[d][fn * 1024 + rbS1]);
                s16x8 b2a = *(const s16x8*)(const void*)(&B2[d][fn * 1024 + rbS0]);
                s16x8 b2b = *(const s16x8*)(const void*)(&B2[d][fn * 1024 + rbS1]);
                acc1[fn] = __builtin_amdgcn_mfma_f32_16x16x32_bf16(a1[0], b1a, acc1[fn], 0, 0, 0);
                acc1[fn] = __builtin_amdgcn_mfma_f32_16x16x32_bf16(a1[1], b1b, acc1[fn], 0, 0, 0);
                acc2[fn] = __builtin_amdgcn_mfma_f32_16x16x32_bf16(a2[0], b2a, acc2[fn], 0, 0, 0);
                acc2[fn] = __builtin_amdgcn_mfma_f32_16x16x32_bf16(a2[1], b2b, acc2[fn], 0, 0, 0);
            }
        }
        __builtin_amdgcn_s_setprio(0);
        __builtin_amdgcn_sched_barrier(0);
        __builtin_amdgcn_s_barrier();
    }
#undef STAGEY

    const float wgate = 1.f / (1.f + __expf(-chainp[0]));
    const int zg = zbase + z;
    const int b_ = zg >> 3, h = zg & 7;
#pragma unroll
    for (int r = 0; r < 4; ++r) {
        const int gm = m0 + arow + g4 * 4 + r;
#pragma unroll
        for (int fn = 0; fn < 4; ++fn) {
            const int gn = fn * 16 + fr;
            const float yv = acc1[fn][r] + wgate * acc2[fn][r];
            yout[((long)(b_ * 2048 + gm)) * 512 + h * 64 + gn] = f2bf(yv);
        }
    }
}

// ============================================================================
// 128x128-tile 2-phase GEMM (QKV / S / final proj).
// ============================================================================
template<int EPI>
__global__ __launch_bounds__(256) void gemm_nt(
    const u16* __restrict__ A, const u16* __restrict__ B,
    long sAz, long sBz, int lda, int ldb,
    int M, int Ncols, int K,
    float* __restrict__ outf, u16* __restrict__ outb,
    u16* __restrict__ outb2, u16* __restrict__ outb3,
    long sOz, int ldc, float scale)
{
    __shared__ __align__(16) u16 As[2][BM * BK];
    __shared__ __align__(16) u16 Bs[2][BN * BK];

    const int z    = blockIdx.z;
    const u16* Ab  = A + (long)z * sAz;
    const u16* Bb  = B + (long)z * sBz;
    const int tid  = threadIdx.x;
    const int lane = tid & 63;
    const int wid  = tid >> 6;
    const int m0   = blockIdx.x * BM;
    const int n0   = blockIdx.y * BN;
    const int wr   = (wid >> 1) * 64;
    const int wc   = (wid & 1) * 64;

    f32x4 zero = {0.f, 0.f, 0.f, 0.f};
    f32x4 acc[4][4];
#pragma unroll
    for (int i = 0; i < 4; ++i)
#pragma unroll
        for (int j = 0; j < 4; ++j) acc[i][j] = zero;

    const int srow = tid >> 2;
    const int scol = (tid & 3) * 8;
    int bn0 = n0 + srow;      if (bn0 > Ncols - 1) bn0 = Ncols - 1;
    int bn1 = n0 + 64 + srow; if (bn1 > Ncols - 1) bn1 = Ncols - 1;
    const u16* gA0 = Ab + (long)(m0 + srow) * lda + scol;
    const u16* gA1 = Ab + (long)(m0 + 64 + srow) * lda + scol;
    const u16* gB0 = Bb + (long)bn0 * ldb + scol;
    const u16* gB1 = Bb + (long)bn1 * ldb + scol;

    const int kq = (lane >> 4) * 8;
    const int fr = lane & 15;

#define STAGE(buf, kk)                                  \
    do {                                                \
        g2lds16(gA0 + (kk), &As[buf][tid * 8]);         \
        g2lds16(gA1 + (kk), &As[buf][2048 + tid * 8]);  \
        g2lds16(gB0 + (kk), &Bs[buf][tid * 8]);         \
        g2lds16(gB1 + (kk), &Bs[buf][2048 + tid * 8]);  \
    } while (0)

    STAGE(0, 0);
    __syncthreads();
    int cur = 0;
    for (int k0 = 0; k0 < K; k0 += BK) {
        if (k0 + BK < K) STAGE(cur ^ 1, k0 + BK);
        s16x8 af[4], bfr[4];
#pragma unroll
        for (int i = 0; i < 4; ++i)
            af[i] = *(const s16x8*)(const void*)(&As[cur][(wr + i * 16 + fr) * BK + kq]);
#pragma unroll
        for (int j = 0; j < 4; ++j)
            bfr[j] = *(const s16x8*)(const void*)(&Bs[cur][(wc + j * 16 + fr) * BK + kq]);
#pragma unroll
        for (int i = 0; i < 4; ++i)
#pragma unroll
            for (int j = 0; j < 4; ++j)
                acc[i][j] = __builtin_amdgcn_mfma_f32_16x16x32_bf16(af[i], bfr[j], acc[i][j], 0, 0, 0);
        __syncthreads();
        cur ^= 1;
    }
#undef STAGE

    const int rbase = (lane >> 4) * 4;
    const int cidx  = lane & 15;

#pragma unroll
    for (int i = 0; i < 4; ++i) {
#pragma unroll
        for (int r = 0; r < 4; ++r) {
            const int gm = m0 + wr + i * 16 + rbase + r;
#pragma unroll
            for (int j = 0; j < 4; ++j) {
                const int gn = n0 + wc + j * 16 + cidx;
                const float v = acc[i][j][r];
                if (EPI == E_F32) {
                    if (gn < Ncols) outf[(long)z * sOz + (long)gm * ldc + gn] = v * scale;
                } else if (EPI == E_BF16) {
                    if (gn < Ncols) outb[(long)z * sOz + (long)gm * ldc + gn] = f2bf(v * scale);
                } else if (EPI == E_QKV) {
                    const int b_ = gm >> 11, ntok = gm & 2047;
                    const int which = gn >> 9, h = (gn & 511) >> 6, d = gn & 63;
                    const long bh = (long)(b_ * 8 + h);
                    const u16 bv = f2bf(which == 0 ? v * scale : v);
                    if (which == 0)       outb [(bh * 2048 + ntok) * 64 + d] = bv;
                    else if (which == 1)  outb2[(bh * 2048 + ntok) * 64 + d] = bv;
                    else                  outb3[(bh * 64 + d) * 2048 + ntok] = bv;
                }
            }
        }
    }
}

__global__ __launch_bounds__(256) void cvt_f32_bf16(const float* __restrict__ in,
                                                    u16* __restrict__ out, long n) {
    long i = (long)blockIdx.x * 256 + threadIdx.x;
    if (i < n) out[i] = f2bf(in[i]);
}

__global__ __launch_bounds__(256) void cvt_transpose(const float* __restrict__ in,
                                                     u16* __restrict__ out, int R, int C) {
    long i = (long)blockIdx.x * 256 + threadIdx.x;
    if (i < (long)R * C) {
        int c = (int)(i / R), r = (int)(i % R);
        out[i] = f2bf(in[(long)r * C + c]);
    }
}

// per-z transpose of 2048x2048 bf16
__global__ __launch_bounds__(256) void trans2048(const u16* __restrict__ in,
                                                 u16* __restrict__ out) {
    __shared__ u16 tile[64][65];
    const long z = blockIdx.z;
    const u16* I = in + z * (long)2048 * 2048;
    u16* O       = out + z * (long)2048 * 2048;
    const int bx = blockIdx.x * 64, by = blockIdx.y * 64;
    const int t = threadIdx.x, c = t & 63, r4 = t >> 6;
#pragma unroll
    for (int s = 0; s < 16; ++s) {
        int r = s * 4 + r4;
        tile[r][c] = I[(long)(by + r) * 2048 + bx + c];
    }
    __syncthreads();
#pragma unroll
    for (int s = 0; s < 16; ++s) {
        int r = s * 4 + r4;
        O[(long)(bx + r) * 2048 + by + c] = tile[c][r];
    }
}

// Fused dual softmax: A1 = softmax(S1); A2 = softmax(S2);
// Pre = 0.5*S1 + 0.75*S2 + 0.5*logaddexp(S1,S2)  (Pre may alias S1).
__global__ __launch_bounds__(256) void sm01(
    const u16* __restrict__ S1, const u16* __restrict__ S2,
    u16* __restrict__ A1, u16* __restrict__ A2, u16* __restrict__ Pre)
{
    const long row = blockIdx.x;
    const int t = threadIdx.x;
    s16x8 v1 = *(const s16x8*)(const void*)(S1 + row * 2048 + t * 8);
    s16x8 v2 = *(const s16x8*)(const void*)(S2 + row * 2048 + t * 8);
    float x1[8], x2[8];
#pragma unroll
    for (int e = 0; e < 8; ++e) { x1[e] = bf2f((u16)v1[e]); x2[e] = bf2f((u16)v2[e]); }
    float m1 = x1[0], m2 = x2[0];
#pragma unroll
    for (int e = 1; e < 8; ++e) { m1 = fmaxf(m1, x1[e]); m2 = fmaxf(m2, x2[e]); }
#pragma unroll
    for (int off = 32; off >= 1; off >>= 1) {
        m1 = fmaxf(m1, __shfl_xor(m1, off));
        m2 = fmaxf(m2, __shfl_xor(m2, off));
    }
    __shared__ float red[16];
    if ((t & 63) == 0) { red[t >> 6] = m1; red[4 + (t >> 6)] = m2; }
    __syncthreads();
    m1 = fmaxf(fmaxf(red[0], red[1]), fmaxf(red[2], red[3]));
    m2 = fmaxf(fmaxf(red[4], red[5]), fmaxf(red[6], red[7]));
    float s1 = 0.f, s2 = 0.f, e1[8], e2[8];
#pragma unroll
    for (int e = 0; e < 8; ++e) {
        e1[e] = __expf(x1[e] - m1); s1 += e1[e];
        e2[e] = __expf(x2[e] - m2); s2 += e2[e];
    }
#pragma unroll
    for (int off = 32; off >= 1; off >>= 1) {
        s1 += __shfl_xor(s1, off);
        s2 += __shfl_xor(s2, off);
    }
    if ((t & 63) == 0) { red[8 + (t >> 6)] = s1; red[12 + (t >> 6)] = s2; }
    __syncthreads();
    s1 = red[8] + red[9] + red[10] + red[11];
    s2 = red[12] + red[13] + red[14] + red[15];
    const float i1 = 1.f / s1, i2 = 1.f / s2;
    s16x8 o1, o2, op;
#pragma unroll
    for (int e = 0; e < 8; ++e) {
        o1[e] = (short)f2bf(e1[e] * i1);
        o2[e] = (short)f2bf(e2[e] * i2);
        const float a = x1[e], b = x2[e];
        const float lae = fmaxf(a, b) + log1pf(__expf(-fabsf(a - b)));
        op[e] = (short)f2bf(0.5f * a + 0.75f * b + 0.5f * lae);
    }
    *(s16x8*)(void*)(A1  + row * 2048 + t * 8) = o1;
    *(s16x8*)(void*)(A2  + row * 2048 + t * 8) = o2;
    *(s16x8*)(void*)(Pre + row * 2048 + t * 8) = op;
}

// One block per row: A = softmax(S)  (final mix softmax)
__global__ __launch_bounds__(256) void row_softmax_bf(
    const u16* __restrict__ S, u16* __restrict__ A)
{
    const long row = blockIdx.x;
    const int t = threadIdx.x;
    s16x8 xv = *(const s16x8*)(const void*)(S + row * 2048 + t * 8);
    float x[8];
#pragma unroll
    for (int e = 0; e < 8; ++e) x[e] = bf2f((u16)xv[e]);
    float m = x[0];
#pragma unroll
    for (int e = 1; e < 8; ++e) m = fmaxf(m, x[e]);
#pragma unroll
    for (int off = 32; off >= 1; off >>= 1) m = fmaxf(m, __shfl_xor(m, off));
    __shared__ float red[8];
    if ((t & 63) == 0) red[t >> 6] = m;
    __syncthreads();
    m = fmaxf(fmaxf(red[0], red[1]), fmaxf(red[2], red[3]));
    float s = 0.f, ee[8];
#pragma unroll
    for (int e = 0; e < 8; ++e) { ee[e] = __expf(x[e] - m); s += ee[e]; }
#pragma unroll
    for (int off = 32; off >= 1; off >>= 1) s += __shfl_xor(s, off);
    if ((t & 63) == 0) red[4 + (t >> 6)] = s;
    __syncthreads();
    s = red[4] + red[5] + red[6] + red[7];
    const float inv = 1.f / s;
    s16x8 o;
#pragma unroll
    for (int e = 0; e < 8; ++e) o[e] = (short)f2bf(ee[e] * inv);
    *(s16x8*)(void*)(A + row * 2048 + t * 8) = o;
}

extern "C" void kernel_launch(void* const* d_in, const int* in_sizes, int n_in,
                              void* d_out, int out_size, void* d_ws, size_t ws_size,
                              hipStream_t stream) {
    const float* x  = (const float*)d_in[0];
    const float* W1 = (const float*)d_in[1];
    const float* W2 = (const float*)d_in[2];
    const float* Wp = (const float*)d_in[3];
    const float* ch = (const float*)d_in[4];

    const int Bq = 2, N = 2048, D = 512, dk = 64, Z = 16;
    const long NN = (long)N * N;
    const long ND = (long)N * dk;
    (void)in_sizes; (void)n_in; (void)out_size;

    size_t ws_avail = ws_size ? ws_size : (size_t)-1;

    char* w = (char*)d_ws;
    size_t off = 0;
    auto alc = [&](size_t bytes) -> void* {
        void* p = w + off;
        off += (bytes + 255) & ~(size_t)255;
        return p;
    };

    // ---- persistent (~36 MiB) ----
    u16* xb   = (u16*)alc((long)Bq * N * D * 2);
    u16* W1t  = (u16*)alc((long)3 * D * D * 2);
    u16* W2t  = (u16*)alc((long)3 * D * D * 2);
    u16* Wpt  = (u16*)alc((long)D * D * 2);
    u16* Q1   = (u16*)alc(Z * ND * 2);
    u16* K1   = (u16*)alc(Z * ND * 2);
    u16* V1t  = (u16*)alc(Z * ND * 2);
    u16* Q2   = (u16*)alc(Z * ND * 2);
    u16* K2   = (u16*)alc(Z * ND * 2);
    u16* V2t  = (u16*)alc(Z * ND * 2);
    u16* y    = (u16*)alc((long)Bq * N * D * 2);
    const size_t persist = off;

    const size_t perz = 4 * (size_t)(NN * 2) + 4096;
    int G = 4;
    while (G > 1 && persist + (size_t)G * perz + 65536 > ws_avail) G >>= 1;

    u16*  S1b = (u16*)alc((size_t)G * NN * 2);   // S1 -> Pre -> Smix
    u16*  S2b = (u16*)alc((size_t)G * NN * 2);   // S2 -> A2t
    u16*  A1b = (u16*)alc((size_t)G * NN * 2);   // A1 -> C2
    u16*  C1b = (u16*)alc((size_t)G * NN * 2);   // A2 -> C1 -> final A

    const dim3 blk(256);
    const float iscale = 0.125f;  // 1/sqrt(64)

    cvt_f32_bf16<<<(unsigned)(((long)Bq * N * D + 255) / 256), blk, 0, stream>>>(x, xb, (long)Bq * N * D);
    cvt_transpose<<<(3 * D * D + 255) / 256, blk, 0, stream>>>(W1, W1t, D, 3 * D);
    cvt_transpose<<<(3 * D * D + 255) / 256, blk, 0, stream>>>(W2, W2t, D, 3 * D);
    cvt_transpose<<<(D * D + 255) / 256, blk, 0, stream>>>(Wp, Wpt, D, D);

    gemm_nt<E_QKV><<<dim3(32, 12, 1), blk, 0, stream>>>(
        xb, W1t, 0L, 0L, D, D, Bq * N, 3 * D, D,
        nullptr, Q1, K1, V1t, 0L, 0, iscale);
    gemm_nt<E_QKV><<<dim3(32, 12, 1), blk, 0, stream>>>(
        xb, W2t, 0L, 0L, D, D, Bq * N, 3 * D, D,
        nullptr, Q2, K2, V2t, 0L, 0, iscale);

    for (int zb = 0; zb < Z; zb += G) {
        const u16* Q1z = Q1 + (long)zb * ND;
        const u16* K1z = K1 + (long)zb * ND;
        const u16* V1z = V1t + (long)zb * ND;
        const u16* Q2z = Q2 + (long)zb * ND;
        const u16* K2z = K2 + (long)zb * ND;
        const u16* V2z = V2t + (long)zb * ND;

        // S1 -> S1b ; S2 -> S2b  (bf16, scale folded into Q)
        gemm_nt<E_BF16><<<dim3(16, 16, G), blk, 0, stream>>>(
            Q1z, K1z, ND, ND, dk, dk, N, N, dk,
            nullptr, S1b, nullptr, nullptr, NN, N, 1.f);
        gemm_nt<E_BF16><<<dim3(16, 16, G), blk, 0, stream>>>(
            Q2z, K2z, ND, ND, dk, dk, N, N, dk,
            nullptr, S2b, nullptr, nullptr, NN, N, 1.f);

        // fused dual softmax: A1 -> A1b ; A2 -> C1b ; Pre -> S1b (in-place)
        sm01<<<G * N, blk, 0, stream>>>(S1b, S2b, A1b, C1b, S1b);

        // A2t: C1b(A2) -> S2b
        trans2048<<<dim3(32, 32, G), blk, 0, stream>>>(C1b, S2b);

        // C1 = A1 @ A2 -> C1b
        gemm256_nt<E_BF16><<<dim3(64, 1, G), dim3(512), 0, stream>>>(
            A1b, S2b, NN, NN, N, N, N,
            C1b, nullptr, nullptr, NN, N);
        // C2 = C1 @ A2 ; Smix = Pre + 0.5*log(C2+eps) -> S1b ; C2 -> A1b
        gemm256_nt<E_SMIX><<<dim3(64, 1, G), dim3(512), 0, stream>>>(
            C1b, S2b, NN, NN, N, N, N,
            S1b, A1b, S1b, NN, N);
        // A = softmax(Smix) -> C1b
        row_softmax_bf<<<G * N, blk, 0, stream>>>(S1b, C1b);

        // y = A@v1 + sigmoid(chain)*(C2@v2)  -> bf16 [B,N,D]
        gemm_y<<<dim3(32, 1, G), blk, 0, stream>>>(
            C1b, A1b, V1z, V2z, y, ch, zb);
    }

    // out = y @ Wproj   (f32)
    gemm_nt<E_F32><<<dim3(32, 4, 1), blk, 0, stream>>>(
        y, Wpt, 0L, 0L, D, D, Bq * N, D, D,
        (float*)d_out, nullptr, nullptr, nullptr, 0L, D, 1.f);
}

// Round 11
// 1229.653 us; speedup vs baseline: 1.1067x; 1.1067x over previous
//
#include <hip/hip_runtime.h>
#include <math.h>

typedef unsigned short u16;
typedef short s16x8 __attribute__((ext_vector_type(8)));
typedef float f32x4 __attribute__((ext_vector_type(4)));

#define BM 128
#define BN 128
#define BK 32

__device__ __forceinline__ u16 f2bf(float f) {
    union { float f; unsigned u; } v; v.f = f;
    unsigned u = v.u + 0x7FFFu + ((v.u >> 16) & 1u);
    return (u16)(u >> 16);
}
__device__ __forceinline__ float bf2f(u16 u) {
    union { unsigned u; float f; } v; v.u = ((unsigned)u) << 16; return v.f;
}

__device__ __forceinline__ void g2lds16(const void* g, void* l) {
    __builtin_amdgcn_global_load_lds(
        (const __attribute__((address_space(1))) void*)g,
        (__attribute__((address_space(3))) void*)l, 16, 0, 0);
}

enum { E_F32 = 0, E_BF16 = 1, E_QKV = 2, E_SMIX = 3 };

// ============================================================================
// 256x256-tile, BK=64, 8-wave counted-vmcnt pipelined GEMM (round-8 proven
// schedule) + rect per-XCD block map (round-10 proven: FETCH 164->115 MB).
// ============================================================================
template<int EPI>
__global__ __launch_bounds__(512) void gemm256_nt(
    const u16* __restrict__ A, const u16* __restrict__ B,
    long sAz, long sBz, int lda, int ldb, int K,
    u16* __restrict__ outb, u16* __restrict__ outb2,
    const u16* __restrict__ aux1b, long sOz, int ldc)
{
    __shared__ __align__(16) u16 As[2][2][8192];
    __shared__ __align__(16) u16 Bs[2][2][8192];

    const int z   = blockIdx.z;
    const u16* Ab = A + (long)z * sAz;
    const u16* Bb = B + (long)z * sBz;
    const int t    = threadIdx.x;
    const int lane = t & 63;
    const int wid  = t >> 6;
    const int wm   = wid >> 2;
    const int wn   = wid & 3;
    const int fr   = lane & 15;
    const int g4   = lane >> 4;

    // rect XCD map: XCD r_=bx&7 owns 2 m-panels x 4 n-panels
    const int bx = blockIdx.x;            // 0..63
    const int r_ = bx & 7, j_ = bx >> 3;  // j_ in [0,8)
    const int m0 = (2 * (r_ & 3) + (j_ & 1)) * 256;
    const int n0 = (4 * (r_ >> 2) + (j_ >> 1)) * 256;

    const int r0 = t >> 3;
    const int xc = ((t & 7) ^ (r0 & 7)) * 8;
    const u16* pA0 = Ab + (long)(m0 + r0) * lda + xc;
    const u16* pA1 = Ab + (long)(m0 + 64 + r0) * lda + xc;
    const u16* pA2 = Ab + (long)(m0 + 128 + r0) * lda + xc;
    const u16* pA3 = Ab + (long)(m0 + 192 + r0) * lda + xc;
    const u16* pB0 = Bb + (long)(n0 + r0) * ldb + xc;
    const u16* pB1 = Bb + (long)(n0 + 64 + r0) * ldb + xc;
    const u16* pB2 = Bb + (long)(n0 + 128 + r0) * ldb + xc;
    const u16* pB3 = Bb + (long)(n0 + 192 + r0) * ldb + xc;
    const int d0 = t * 8;
    const int d1 = t * 8 + 4096;

#define STAGE256(d, kk)                        \
    do {                                       \
        g2lds16(pA0 + (kk), &As[d][0][d0]);    \
        g2lds16(pA1 + (kk), &As[d][0][d1]);    \
        g2lds16(pA2 + (kk), &As[d][1][d0]);    \
        g2lds16(pA3 + (kk), &As[d][1][d1]);    \
        g2lds16(pB0 + (kk), &Bs[d][0][d0]);    \
        g2lds16(pB1 + (kk), &Bs[d][0][d1]);    \
        g2lds16(pB2 + (kk), &Bs[d][1][d0]);    \
        g2lds16(pB3 + (kk), &Bs[d][1][d1]);    \
    } while (0)

    const int swz  = fr & 7;
    const int rbS0 = fr * 64 + ((g4 ^ swz) * 8);
    const int rbS1 = fr * 64 + (((4 + g4) ^ swz) * 8);

    f32x4 acc[8][4];
#pragma unroll
    for (int i = 0; i < 8; ++i)
#pragma unroll
        for (int j = 0; j < 4; ++j) acc[i][j] = (f32x4){0.f, 0.f, 0.f, 0.f};

    STAGE256(0, 0);
    const int NT = K >> 6;
    for (int T = 0; T < NT; ++T) {
        const int d = T & 1;
        if (T + 1 < NT) {
            STAGE256(d ^ 1, (T + 1) << 6);
            asm volatile("s_waitcnt vmcnt(8)" ::: "memory");
        } else {
            asm volatile("s_waitcnt vmcnt(0)" ::: "memory");
        }
        __builtin_amdgcn_s_barrier();
        __builtin_amdgcn_sched_barrier(0);
        __builtin_amdgcn_s_setprio(1);
        {
            const u16* Abase = &As[d][wm][0];
            const u16* Bbase = &Bs[d][wn >> 1][(wn & 1) * 4096];
            s16x8 bv[4][2];
#pragma unroll
            for (int fn = 0; fn < 4; ++fn) {
                bv[fn][0] = *(const s16x8*)(const void*)(Bbase + fn * 1024 + rbS0);
                bv[fn][1] = *(const s16x8*)(const void*)(Bbase + fn * 1024 + rbS1);
            }
#pragma unroll
            for (int h = 0; h < 2; ++h) {
                s16x8 av[4][2];
#pragma unroll
                for (int fm = 0; fm < 4; ++fm) {
                    av[fm][0] = *(const s16x8*)(const void*)(Abase + (h * 4 + fm) * 1024 + rbS0);
                    av[fm][1] = *(const s16x8*)(const void*)(Abase + (h * 4 + fm) * 1024 + rbS1);
                }
#pragma unroll
                for (int fm = 0; fm < 4; ++fm)
#pragma unroll
                    for (int fn = 0; fn < 4; ++fn) {
                        acc[h * 4 + fm][fn] = __builtin_amdgcn_mfma_f32_16x16x32_bf16(
                            av[fm][0], bv[fn][0], acc[h * 4 + fm][fn], 0, 0, 0);
                        acc[h * 4 + fm][fn] = __builtin_amdgcn_mfma_f32_16x16x32_bf16(
                            av[fm][1], bv[fn][1], acc[h * 4 + fm][fn], 0, 0, 0);
                    }
            }
        }
        __builtin_amdgcn_s_setprio(0);
        __builtin_amdgcn_sched_barrier(0);
        __builtin_amdgcn_s_barrier();
    }
#undef STAGE256

#pragma unroll
    for (int fm = 0; fm < 8; ++fm) {
#pragma unroll
        for (int r = 0; r < 4; ++r) {
            const int gm = m0 + wm * 128 + fm * 16 + g4 * 4 + r;
#pragma unroll
            for (int fn = 0; fn < 4; ++fn) {
                const int gn = n0 + wn * 64 + fn * 16 + fr;
                const float v = acc[fm][fn][r];
                const long off = (long)z * sOz + (long)gm * ldc + gn;
                if (EPI == E_BF16) {
                    outb[off] = f2bf(v);
                } else {  // E_SMIX
                    const float pre = bf2f(aux1b[off]);
                    outb[off]  = f2bf(pre + 0.5f * __logf(v + 1e-6f));
                    outb2[off] = f2bf(v);
                }
            }
        }
    }
}

// ============================================================================
// Fused final: y = A@v1 + w*(C2@v2).  BM=64, BN=64(=dk), BK=64, 4 waves.
// ============================================================================
__global__ __launch_bounds__(256) void gemm_y(
    const u16* __restrict__ Amat, const u16* __restrict__ C2mat,
    const u16* __restrict__ V1t, const u16* __restrict__ V2t,
    u16* __restrict__ yout, const float* __restrict__ chainp, int zbase)
{
    __shared__ __align__(16) u16 Aa[2][4096];
    __shared__ __align__(16) u16 Ac[2][4096];
    __shared__ __align__(16) u16 B1[2][4096];
    __shared__ __align__(16) u16 B2[2][4096];

    const long NNl = 2048L * 2048;
    const long NDl = 2048L * 64;
    const int z = blockIdx.z;
    const u16* Ab  = Amat  + z * NNl;
    const u16* Cb  = C2mat + z * NNl;
    const u16* V1b = V1t + z * NDl;
    const u16* V2b = V2t + z * NDl;

    const int t = threadIdx.x;
    const int lane = t & 63, wv = t >> 6;
    const int fr = lane & 15, g4 = lane >> 4;
    const int m0 = blockIdx.x * 64;

    const int sr = t >> 3;
    const int sg = t & 7;
    const int c0 = (sg ^ (sr & 7)) * 8;
    const int c1 = (sg ^ ((sr + 32) & 7)) * 8;
    const u16* pAa0 = Ab  + (long)(m0 + sr) * 2048 + c0;
    const u16* pAa1 = Ab  + (long)(m0 + 32 + sr) * 2048 + c1;
    const u16* pAc0 = Cb  + (long)(m0 + sr) * 2048 + c0;
    const u16* pAc1 = Cb  + (long)(m0 + 32 + sr) * 2048 + c1;
    const u16* pB10 = V1b + (long)sr * 2048 + c0;
    const u16* pB11 = V1b + (long)(32 + sr) * 2048 + c1;
    const u16* pB20 = V2b + (long)sr * 2048 + c0;
    const u16* pB21 = V2b + (long)(32 + sr) * 2048 + c1;
    const int e0 = t * 8, e1 = t * 8 + 2048;

#define STAGEY(d, kk)                          \
    do {                                       \
        g2lds16(pAa0 + (kk), &Aa[d][e0]);      \
        g2lds16(pAa1 + (kk), &Aa[d][e1]);      \
        g2lds16(pAc0 + (kk), &Ac[d][e0]);      \
        g2lds16(pAc1 + (kk), &Ac[d][e1]);      \
        g2lds16(pB10 + (kk), &B1[d][e0]);      \
        g2lds16(pB11 + (kk), &B1[d][e1]);      \
        g2lds16(pB20 + (kk), &B2[d][e0]);      \
        g2lds16(pB21 + (kk), &B2[d][e1]);      \
    } while (0)

    const int swz  = fr & 7;
    const int rbS0 = fr * 64 + ((g4 ^ swz) * 8);
    const int rbS1 = fr * 64 + (((4 + g4) ^ swz) * 8);
    const int arow = wv * 16;

    f32x4 acc1[4], acc2[4];
#pragma unroll
    for (int j = 0; j < 4; ++j) { acc1[j] = (f32x4){0,0,0,0}; acc2[j] = (f32x4){0,0,0,0}; }

    STAGEY(0, 0);
    for (int T = 0; T < 32; ++T) {
        const int d = T & 1;
        if (T + 1 < 32) {
            STAGEY(d ^ 1, (T + 1) << 6);
            asm volatile("s_waitcnt vmcnt(8)" ::: "memory");
        } else {
            asm volatile("s_waitcnt vmcnt(0)" ::: "memory");
        }
        __builtin_amdgcn_s_barrier();
        __builtin_amdgcn_sched_barrier(0);
        __builtin_amdgcn_s_setprio(1);
        {
            s16x8 a1[2], a2[2];
            a1[0] = *(const s16x8*)(const void*)(&Aa[d][arow * 64 + rbS0]);
            a1[1] = *(const s16x8*)(const void*)(&Aa[d][arow * 64 + rbS1]);
            a2[0] = *(const s16x8*)(const void*)(&Ac[d][arow * 64 + rbS0]);
            a2[1] = *(const s16x8*)(const void*)(&Ac[d][arow * 64 + rbS1]);
#pragma unroll
            for (int fn = 0; fn < 4; ++fn) {
                s16x8 b1a = *(const s16x8*)(const void*)(&B1[d][fn * 1024 + rbS0]);
                s16x8 b1b = *(const s16x8*)(const void*)(&B1[d][fn * 1024 + rbS1]);
                s16x8 b2a = *(const s16x8*)(const void*)(&B2[d][fn * 1024 + rbS0]);
                s16x8 b2b = *(const s16x8*)(const void*)(&B2[d][fn * 1024 + rbS1]);
                acc1[fn] = __builtin_amdgcn_mfma_f32_16x16x32_bf16(a1[0], b1a, acc1[fn], 0, 0, 0);
                acc1[fn] = __builtin_amdgcn_mfma_f32_16x16x32_bf16(a1[1], b1b, acc1[fn], 0, 0, 0);
                acc2[fn] = __builtin_amdgcn_mfma_f32_16x16x32_bf16(a2[0], b2a, acc2[fn], 0, 0, 0);
                acc2[fn] = __builtin_amdgcn_mfma_f32_16x16x32_bf16(a2[1], b2b, acc2[fn], 0, 0, 0);
            }
        }
        __builtin_amdgcn_s_setprio(0);
        __builtin_amdgcn_sched_barrier(0);
        __builtin_amdgcn_s_barrier();
    }
#undef STAGEY

    const float wgate = 1.f / (1.f + __expf(-chainp[0]));
    const int zg = zbase + z;
    const int b_ = zg >> 3, h = zg & 7;
#pragma unroll
    for (int r = 0; r < 4; ++r) {
        const int gm = m0 + arow + g4 * 4 + r;
#pragma unroll
        for (int fn = 0; fn < 4; ++fn) {
            const int gn = fn * 16 + fr;
            const float yv = acc1[fn][r] + wgate * acc2[fn][r];
            yout[((long)(b_ * 2048 + gm)) * 512 + h * 64 + gn] = f2bf(yv);
        }
    }
}

// ============================================================================
// 128x128-tile 2-phase GEMM (QKV / S / final proj).
// ============================================================================
template<int EPI>
__global__ __launch_bounds__(256) void gemm_nt(
    const u16* __restrict__ A, const u16* __restrict__ B,
    long sAz, long sBz, int lda, int ldb,
    int M, int Ncols, int K,
    float* __restrict__ outf, u16* __restrict__ outb,
    u16* __restrict__ outb2, u16* __restrict__ outb3,
    long sOz, int ldc, float scale)
{
    __shared__ __align__(16) u16 As[2][BM * BK];
    __shared__ __align__(16) u16 Bs[2][BN * BK];

    const int z    = blockIdx.z;
    const u16* Ab  = A + (long)z * sAz;
    const u16* Bb  = B + (long)z * sBz;
    const int tid  = threadIdx.x;
    const int lane = tid & 63;
    const int wid  = tid >> 6;
    const int m0   = blockIdx.x * BM;
    const int n0   = blockIdx.y * BN;
    const int wr   = (wid >> 1) * 64;
    const int wc   = (wid & 1) * 64;

    f32x4 zero = {0.f, 0.f, 0.f, 0.f};
    f32x4 acc[4][4];
#pragma unroll
    for (int i = 0; i < 4; ++i)
#pragma unroll
        for (int j = 0; j < 4; ++j) acc[i][j] = zero;

    const int srow = tid >> 2;
    const int scol = (tid & 3) * 8;
    int bn0 = n0 + srow;      if (bn0 > Ncols - 1) bn0 = Ncols - 1;
    int bn1 = n0 + 64 + srow; if (bn1 > Ncols - 1) bn1 = Ncols - 1;
    const u16* gA0 = Ab + (long)(m0 + srow) * lda + scol;
    const u16* gA1 = Ab + (long)(m0 + 64 + srow) * lda + scol;
    const u16* gB0 = Bb + (long)bn0 * ldb + scol;
    const u16* gB1 = Bb + (long)bn1 * ldb + scol;

    const int kq = (lane >> 4) * 8;
    const int fr = lane & 15;

#define STAGE(buf, kk)                                  \
    do {                                                \
        g2lds16(gA0 + (kk), &As[buf][tid * 8]);         \
        g2lds16(gA1 + (kk), &As[buf][2048 + tid * 8]);  \
        g2lds16(gB0 + (kk), &Bs[buf][tid * 8]);         \
        g2lds16(gB1 + (kk), &Bs[buf][2048 + tid * 8]);  \
    } while (0)

    STAGE(0, 0);
    __syncthreads();
    int cur = 0;
    for (int k0 = 0; k0 < K; k0 += BK) {
        if (k0 + BK < K) STAGE(cur ^ 1, k0 + BK);
        s16x8 af[4], bfr[4];
#pragma unroll
        for (int i = 0; i < 4; ++i)
            af[i] = *(const s16x8*)(const void*)(&As[cur][(wr + i * 16 + fr) * BK + kq]);
#pragma unroll
        for (int j = 0; j < 4; ++j)
            bfr[j] = *(const s16x8*)(const void*)(&Bs[cur][(wc + j * 16 + fr) * BK + kq]);
#pragma unroll
        for (int i = 0; i < 4; ++i)
#pragma unroll
            for (int j = 0; j < 4; ++j)
                acc[i][j] = __builtin_amdgcn_mfma_f32_16x16x32_bf16(af[i], bfr[j], acc[i][j], 0, 0, 0);
        __syncthreads();
        cur ^= 1;
    }
#undef STAGE

    const int rbase = (lane >> 4) * 4;
    const int cidx  = lane & 15;

#pragma unroll
    for (int i = 0; i < 4; ++i) {
#pragma unroll
        for (int r = 0; r < 4; ++r) {
            const int gm = m0 + wr + i * 16 + rbase + r;
#pragma unroll
            for (int j = 0; j < 4; ++j) {
                const int gn = n0 + wc + j * 16 + cidx;
                const float v = acc[i][j][r];
                if (EPI == E_F32) {
                    if (gn < Ncols) outf[(long)z * sOz + (long)gm * ldc + gn] = v * scale;
                } else if (EPI == E_BF16) {
                    if (gn < Ncols) outb[(long)z * sOz + (long)gm * ldc + gn] = f2bf(v * scale);
                } else if (EPI == E_QKV) {
                    const int b_ = gm >> 11, ntok = gm & 2047;
                    const int which = gn >> 9, h = (gn & 511) >> 6, d = gn & 63;
                    const long bh = (long)(b_ * 8 + h);
                    const u16 bv = f2bf(which == 0 ? v * scale : v);
                    if (which == 0)       outb [(bh * 2048 + ntok) * 64 + d] = bv;
                    else if (which == 1)  outb2[(bh * 2048 + ntok) * 64 + d] = bv;
                    else                  outb3[(bh * 64 + d) * 2048 + ntok] = bv;
                }
            }
        }
    }
}

__global__ __launch_bounds__(256) void cvt_f32_bf16(const float* __restrict__ in,
                                                    u16* __restrict__ out, long n) {
    long i = (long)blockIdx.x * 256 + threadIdx.x;
    if (i < n) out[i] = f2bf(in[i]);
}

__global__ __launch_bounds__(256) void cvt_transpose(const float* __restrict__ in,
                                                     u16* __restrict__ out, int R, int C) {
    long i = (long)blockIdx.x * 256 + threadIdx.x;
    if (i < (long)R * C) {
        int c = (int)(i / R), r = (int)(i % R);
        out[i] = f2bf(in[(long)r * C + c]);
    }
}

// per-z transpose of 2048x2048 bf16 — 16B/lane global both directions
__global__ __launch_bounds__(256) void trans2048(const u16* __restrict__ in,
                                                 u16* __restrict__ out) {
    __shared__ u16 tile[64][65];
    const long z = blockIdx.z;
    const u16* I = in + z * (long)2048 * 2048;
    u16* O       = out + z * (long)2048 * 2048;
    const int bx = blockIdx.x * 64, by = blockIdx.y * 64;
    const int t = threadIdx.x;
    const int r = t >> 3, c0 = (t & 7) * 8;
#pragma unroll
    for (int p = 0; p < 2; ++p) {
        const int rr = r + p * 32;
        s16x8 v = *(const s16x8*)(const void*)(I + (long)(by + rr) * 2048 + bx + c0);
#pragma unroll
        for (int e = 0; e < 8; ++e) tile[rr][c0 + e] = (u16)v[e];
    }
    __syncthreads();
#pragma unroll
    for (int p = 0; p < 2; ++p) {
        const int rr = r + p * 32;
        s16x8 v;
#pragma unroll
        for (int e = 0; e < 8; ++e) v[e] = (short)tile[c0 + e][rr];
        *(s16x8*)(void*)(O + (long)(bx + rr) * 2048 + by + c0) = v;
    }
}

// Fused dual softmax: A1 = softmax(S1); A2 = softmax(S2);
// Pre = 0.5*S1 + 0.75*S2 + 0.5*logaddexp(S1,S2)  (Pre may alias S1).
__global__ __launch_bounds__(256) void sm01(
    const u16* __restrict__ S1, const u16* __restrict__ S2,
    u16* __restrict__ A1, u16* __restrict__ A2, u16* __restrict__ Pre)
{
    const long row = blockIdx.x;
    const int t = threadIdx.x;
    s16x8 v1 = *(const s16x8*)(const void*)(S1 + row * 2048 + t * 8);
    s16x8 v2 = *(const s16x8*)(const void*)(S2 + row * 2048 + t * 8);
    float x1[8], x2[8];
#pragma unroll
    for (int e = 0; e < 8; ++e) { x1[e] = bf2f((u16)v1[e]); x2[e] = bf2f((u16)v2[e]); }
    float m1 = x1[0], m2 = x2[0];
#pragma unroll
    for (int e = 1; e < 8; ++e) { m1 = fmaxf(m1, x1[e]); m2 = fmaxf(m2, x2[e]); }
#pragma unroll
    for (int off = 32; off >= 1; off >>= 1) {
        m1 = fmaxf(m1, __shfl_xor(m1, off));
        m2 = fmaxf(m2, __shfl_xor(m2, off));
    }
    __shared__ float red[16];
    if ((t & 63) == 0) { red[t >> 6] = m1; red[4 + (t >> 6)] = m2; }
    __syncthreads();
    m1 = fmaxf(fmaxf(red[0], red[1]), fmaxf(red[2], red[3]));
    m2 = fmaxf(fmaxf(red[4], red[5]), fmaxf(red[6], red[7]));
    float s1 = 0.f, s2 = 0.f, e1[8], e2[8];
#pragma unroll
    for (int e = 0; e < 8; ++e) {
        e1[e] = __expf(x1[e] - m1); s1 += e1[e];
        e2[e] = __expf(x2[e] - m2); s2 += e2[e];
    }
#pragma unroll
    for (int off = 32; off >= 1; off >>= 1) {
        s1 += __shfl_xor(s1, off);
        s2 += __shfl_xor(s2, off);
    }
    if ((t & 63) == 0) { red[8 + (t >> 6)] = s1; red[12 + (t >> 6)] = s2; }
    __syncthreads();
    s1 = red[8] + red[9] + red[10] + red[11];
    s2 = red[12] + red[13] + red[14] + red[15];
    const float i1 = 1.f / s1, i2 = 1.f / s2;
    s16x8 o1, o2, op;
#pragma unroll
    for (int e = 0; e < 8; ++e) {
        o1[e] = (short)f2bf(e1[e] * i1);
        o2[e] = (short)f2bf(e2[e] * i2);
        const float a = x1[e], b = x2[e];
        const float lae = fmaxf(a, b) + log1pf(__expf(-fabsf(a - b)));
        op[e] = (short)f2bf(0.5f * a + 0.75f * b + 0.5f * lae);
    }
    *(s16x8*)(void*)(A1  + row * 2048 + t * 8) = o1;
    *(s16x8*)(void*)(A2  + row * 2048 + t * 8) = o2;
    *(s16x8*)(void*)(Pre + row * 2048 + t * 8) = op;
}

// One block per row: A = softmax(S)  (final mix softmax)
__global__ __launch_bounds__(256) void row_softmax_bf(
    const u16* __restrict__ S, u16* __restrict__ A)
{
    const long row = blockIdx.x;
    const int t = threadIdx.x;
    s16x8 xv = *(const s16x8*)(const void*)(S + row * 2048 + t * 8);
    float x[8];
#pragma unroll
    for (int e = 0; e < 8; ++e) x[e] = bf2f((u16)xv[e]);
    float m = x[0];
#pragma unroll
    for (int e = 1; e < 8; ++e) m = fmaxf(m, x[e]);
#pragma unroll
    for (int off = 32; off >= 1; off >>= 1) m = fmaxf(m, __shfl_xor(m, off));
    __shared__ float red[8];
    if ((t & 63) == 0) red[t >> 6] = m;
    __syncthreads();
    m = fmaxf(fmaxf(red[0], red[1]), fmaxf(red[2], red[3]));
    float s = 0.f, ee[8];
#pragma unroll
    for (int e = 0; e < 8; ++e) { ee[e] = __expf(x[e] - m); s += ee[e]; }
#pragma unroll
    for (int off = 32; off >= 1; off >>= 1) s += __shfl_xor(s, off);
    if ((t & 63) == 0) red[4 + (t >> 6)] = s;
    __syncthreads();
    s = red[4] + red[5] + red[6] + red[7];
    const float inv = 1.f / s;
    s16x8 o;
#pragma unroll
    for (int e = 0; e < 8; ++e) o[e] = (short)f2bf(ee[e] * inv);
    *(s16x8*)(void*)(A + row * 2048 + t * 8) = o;
}

extern "C" void kernel_launch(void* const* d_in, const int* in_sizes, int n_in,
                              void* d_out, int out_size, void* d_ws, size_t ws_size,
                              hipStream_t stream) {
    const float* x  = (const float*)d_in[0];
    const float* W1 = (const float*)d_in[1];
    const float* W2 = (const float*)d_in[2];
    const float* Wp = (const float*)d_in[3];
    const float* ch = (const float*)d_in[4];

    const int Bq = 2, N = 2048, D = 512, dk = 64, Z = 16;
    const long NN = (long)N * N;
    const long ND = (long)N * dk;
    (void)in_sizes; (void)n_in; (void)out_size;

    size_t ws_avail = ws_size ? ws_size : (size_t)-1;

    char* w = (char*)d_ws;
    size_t off = 0;
    auto alc = [&](size_t bytes) -> void* {
        void* p = w + off;
        off += (bytes + 255) & ~(size_t)255;
        return p;
    };

    // ---- persistent (~36 MiB) ----
    u16* xb   = (u16*)alc((long)Bq * N * D * 2);
    u16* W1t  = (u16*)alc((long)3 * D * D * 2);
    u16* W2t  = (u16*)alc((long)3 * D * D * 2);
    u16* Wpt  = (u16*)alc((long)D * D * 2);
    u16* Q1   = (u16*)alc(Z * ND * 2);
    u16* K1   = (u16*)alc(Z * ND * 2);
    u16* V1t  = (u16*)alc(Z * ND * 2);
    u16* Q2   = (u16*)alc(Z * ND * 2);
    u16* K2   = (u16*)alc(Z * ND * 2);
    u16* V2t  = (u16*)alc(Z * ND * 2);
    u16* y    = (u16*)alc((long)Bq * N * D * 2);
    const size_t persist = off;

    const size_t perz = 4 * (size_t)(NN * 2) + 4096;
    int G = 4;
    while (G > 1 && persist + (size_t)G * perz + 65536 > ws_avail) G >>= 1;

    u16*  S1b = (u16*)alc((size_t)G * NN * 2);   // S1 -> Pre -> Smix
    u16*  S2b = (u16*)alc((size_t)G * NN * 2);   // S2 -> A2t
    u16*  A1b = (u16*)alc((size_t)G * NN * 2);   // A1 -> C2
    u16*  C1b = (u16*)alc((size_t)G * NN * 2);   // A2 -> C1 -> final A

    const dim3 blk(256);
    const float iscale = 0.125f;  // 1/sqrt(64)

    cvt_f32_bf16<<<(unsigned)(((long)Bq * N * D + 255) / 256), blk, 0, stream>>>(x, xb, (long)Bq * N * D);
    cvt_transpose<<<(3 * D * D + 255) / 256, blk, 0, stream>>>(W1, W1t, D, 3 * D);
    cvt_transpose<<<(3 * D * D + 255) / 256, blk, 0, stream>>>(W2, W2t, D, 3 * D);
    cvt_transpose<<<(D * D + 255) / 256, blk, 0, stream>>>(Wp, Wpt, D, D);

    gemm_nt<E_QKV><<<dim3(32, 12, 1), blk, 0, stream>>>(
        xb, W1t, 0L, 0L, D, D, Bq * N, 3 * D, D,
        nullptr, Q1, K1, V1t, 0L, 0, iscale);
    gemm_nt<E_QKV><<<dim3(32, 12, 1), blk, 0, stream>>>(
        xb, W2t, 0L, 0L, D, D, Bq * N, 3 * D, D,
        nullptr, Q2, K2, V2t, 0L, 0, iscale);

    for (int zb = 0; zb < Z; zb += G) {
        const u16* Q1z = Q1 + (long)zb * ND;
        const u16* K1z = K1 + (long)zb * ND;
        const u16* V1z = V1t + (long)zb * ND;
        const u16* Q2z = Q2 + (long)zb * ND;
        const u16* K2z = K2 + (long)zb * ND;
        const u16* V2z = V2t + (long)zb * ND;

        // S1 -> S1b ; S2 -> S2b  (bf16, scale folded into Q)
        gemm_nt<E_BF16><<<dim3(16, 16, G), blk, 0, stream>>>(
            Q1z, K1z, ND, ND, dk, dk, N, N, dk,
            nullptr, S1b, nullptr, nullptr, NN, N, 1.f);
        gemm_nt<E_BF16><<<dim3(16, 16, G), blk, 0, stream>>>(
            Q2z, K2z, ND, ND, dk, dk, N, N, dk,
            nullptr, S2b, nullptr, nullptr, NN, N, 1.f);

        // fused dual softmax: A1 -> A1b ; A2 -> C1b ; Pre -> S1b (in-place)
        sm01<<<G * N, blk, 0, stream>>>(S1b, S2b, A1b, C1b, S1b);

        // A2t: C1b(A2) -> S2b
        trans2048<<<dim3(32, 32, G), blk, 0, stream>>>(C1b, S2b);

        // C1 = A1 @ A2 -> C1b
        gemm256_nt<E_BF16><<<dim3(64, 1, G), dim3(512), 0, stream>>>(
            A1b, S2b, NN, NN, N, N, N,
            C1b, nullptr, nullptr, NN, N);
        // C2 = C1 @ A2 ; Smix = Pre + 0.5*log(C2+eps) -> S1b ; C2 -> A1b
        gemm256_nt<E_SMIX><<<dim3(64, 1, G), dim3(512), 0, stream>>>(
            C1b, S2b, NN, NN, N, N, N,
            S1b, A1b, S1b, NN, N);
        // A = softmax(Smix) -> C1b
        row_softmax_bf<<<G * N, blk, 0, stream>>>(S1b, C1b);

        // y = A@v1 + sigmoid(chain)*(C2@v2)  -> bf16 [B,N,D]
        gemm_y<<<dim3(32, 1, G), blk, 0, stream>>>(
            C1b, A1b, V1z, V2z, y, ch, zb);
    }

    // out = y @ Wproj   (f32)
    gemm_nt<E_F32><<<dim3(32, 4, 1), blk, 0, stream>>>(
        y, Wpt, 0L, 0L, D, D, Bq * N, D, D,
        (float*)d_out, nullptr, nullptr, nullptr, 0L, D, 1.f);
}